// Round 7
// baseline (253.024 us; speedup 1.0000x reference)
//
#include <hip/hip_runtime.h>
#include <hip/hip_bf16.h>
#include <math.h>

#define DIMC 1024
#define NHEAD 16
#define HDIM 64
#define MPAD 12288   // 12224 padded up to multiple of 256

using bf16x8 = __attribute__((ext_vector_type(8))) short;
using f32x4  = __attribute__((ext_vector_type(4))) float;
using f32x16 = __attribute__((ext_vector_type(16))) float;

__device__ inline ushort f2bf(float f) {          // round-to-nearest-even
    uint u = __float_as_uint(f);
    u += 0x7fffu + ((u >> 16) & 1u);
    return (ushort)(u >> 16);
}
__device__ inline float bf2f(ushort h) { return __uint_as_float(((uint)h) << 16); }

__device__ inline uint pkbf(float a, float b) {   // pack 2 f32 -> 2 bf16 (lo=a)
    __hip_bfloat162 t = __float22bfloat162_rn(float2{a, b});
    return *reinterpret_cast<uint*>(&t);
}

__device__ inline void gload_lds16(const ushort* g, ushort* l) {
    __builtin_amdgcn_global_load_lds(
        (const __attribute__((address_space(1))) uint*)g,
        (__attribute__((address_space(3))) uint*)l, 16, 0, 0);
}

// ---------------------------------------------------------------------------
// 256x256 4-phase counted-vmcnt bf16 GEMM (T2+T3+T4+T5).
//   C[M x (ntTiles*256)] = A[MPAD x 1024] * Bt[(ntTiles*256) x 1024]^T + bias
// 8 waves (2M x 4N), BK=64, LDS 128KB dbuf, XOR-swizzled reads with
// inverse-swizzled global_load_lds sources, per-wave staging ownership:
// wave stages exactly the quarters it consumes -> counted vmcnt(4)/(6)/(6).
// Sync ledger (steady state, per wave, 8 loads/K-tile issued p0:4 p1:2 p2:2):
//   p0 wait vmcnt(4): retires Aq0,Bq0 (oldest 4 of 8)  -> read qr0,qc0
//   p1 wait vmcnt(6): retires Bq1                      -> read qc1
//   p2 wait vmcnt(6): retires Aq1                      -> read qr1
// Raw s_barrier (no drain) after each wait; writes of tile t+2 into buf[cur]
// only occur after p0's barrier, i.e. after all iter-t reads of buf[cur].
// ---------------------------------------------------------------------------
template <bool BF16OUT>
__global__ __launch_bounds__(512, 2) void gemm256(
    const ushort* __restrict__ A, const ushort* __restrict__ Bt,
    const float* __restrict__ bias0, const float* __restrict__ bias1,
    const float* __restrict__ bias2,
    void* __restrict__ out0, void* __restrict__ out1, void* __restrict__ out2,
    int M, int mtPerXcd, int mtTotal)
{
    __shared__ ushort lds[2][2][256 * 64];   // [buf][A=0/B=1][row*64 + k]

    const int bid = blockIdx.x;
    const int xcd = bid & 7;
    const int j   = bid >> 3;
    const int mt  = xcd * mtPerXcd + (j % mtPerXcd);
    const int nt  = j / mtPerXcd;
    const int row0 = mt * 256;
    const int col0 = nt * 256;               // within Bt's row dim

    const int t512 = threadIdx.x;
    const int w    = t512 >> 6;
    const int lane = t512 & 63;
    const int wm   = w >> 2;                 // 0..1
    const int wn   = w & 3;                  // 0..3
    const int l15  = lane & 15;
    const int kh   = lane >> 4;              // 0..3

    // ---- staging: one gload_lds call covers 8 rows x 64k (1KB), linear LDS;
    // global source is inverse-swizzled so swizzled READS see correct data.
    auto stage = [&](int buf, int kt, int mat, int relRow) {
        const int o   = relRow * 128 + lane * 16;          // byte off in tile
        const int row = o >> 7;
        const int kb  = (o & 127) ^ ((row & 7) << 4);
        const ushort* src = (mat ? Bt + (size_t)(col0 + row) * DIMC
                                 : A  + (size_t)(row0 + row) * DIMC)
                            + kt * 64 + (kb >> 1);
        gload_lds16(src, &lds[buf][mat][0] + relRow * 64);
    };

    // ---- swizzled ds_read of one bf16x8 fragment
    auto rdA = [&](int buf, int qr, int fr, int ks) -> bf16x8 {
        const int row = wm * 128 + qr * 64 + fr * 16 + l15;
        const int ad  = (row * 128 + ks * 64 + kh * 16) ^ ((row & 7) << 4);
        return *(const bf16x8*)(&lds[buf][0][0] + (ad >> 1));
    };
    auto rdB = [&](int buf, int qc, int fc, int ks) -> bf16x8 {
        const int row = wn * 64 + qc * 32 + fc * 16 + l15;
        const int ad  = (row * 128 + ks * 64 + kh * 16) ^ ((row & 7) << 4);
        return *(const bf16x8*)(&lds[buf][1][0] + (ad >> 1));
    };

    f32x4 acc[8][4] = {};
    bf16x8 af[4][2];         // current A-half frags
    bf16x8 bq[2][2][2];      // [qc][fc][ks], both halves stay live

    // ---- prologue: stage tile 0 into buf 0, steady-state issue order
    stage(0, 0, 0, wm * 128 + wn * 16);           // Aq0
    stage(0, 0, 0, wm * 128 + wn * 16 + 8);
    stage(0, 0, 1, wn * 64 + wm * 16);            // Bq0
    stage(0, 0, 1, wn * 64 + wm * 16 + 8);
    stage(0, 0, 1, wn * 64 + 32 + wm * 16);       // Bq1
    stage(0, 0, 1, wn * 64 + 32 + wm * 16 + 8);
    stage(0, 0, 0, wm * 128 + 64 + wn * 16);      // Aq1
    stage(0, 0, 0, wm * 128 + 64 + wn * 16 + 8);

    const int NT = DIMC / 64;    // 16 K-tiles
    for (int t = 0; t < NT; ++t) {
        const int cur = t & 1;
        const int nxt = cur ^ 1;
        const int tn  = (t + 1 < NT) ? (t + 1) : (NT - 1);  // last iter: restage (dead buf)

        // ================= phase 0: quadrant (qr0, qc0) =================
        asm volatile("s_waitcnt vmcnt(4)" ::: "memory");
        __builtin_amdgcn_s_barrier();
        __builtin_amdgcn_sched_barrier(0);
        #pragma unroll
        for (int fr = 0; fr < 4; ++fr)
            #pragma unroll
            for (int ks = 0; ks < 2; ++ks)
                af[fr][ks] = rdA(cur, 0, fr, ks);
        #pragma unroll
        for (int fc = 0; fc < 2; ++fc)
            #pragma unroll
            for (int ks = 0; ks < 2; ++ks)
                bq[0][fc][ks] = rdB(cur, 0, fc, ks);
        stage(nxt, tn, 0, wm * 128 + wn * 16);
        stage(nxt, tn, 0, wm * 128 + wn * 16 + 8);
        stage(nxt, tn, 1, wn * 64 + wm * 16);
        stage(nxt, tn, 1, wn * 64 + wm * 16 + 8);
        __builtin_amdgcn_s_setprio(1);
        #pragma unroll
        for (int fr = 0; fr < 4; ++fr)
            #pragma unroll
            for (int fc = 0; fc < 2; ++fc)
                #pragma unroll
                for (int ks = 0; ks < 2; ++ks)
                    acc[fr][fc] = __builtin_amdgcn_mfma_f32_16x16x32_bf16(
                        af[fr][ks], bq[0][fc][ks], acc[fr][fc], 0, 0, 0);
        __builtin_amdgcn_s_setprio(0);

        // ================= phase 1: quadrant (qr0, qc1) =================
        asm volatile("s_waitcnt vmcnt(6)" ::: "memory");
        __builtin_amdgcn_s_barrier();
        __builtin_amdgcn_sched_barrier(0);
        #pragma unroll
        for (int fc = 0; fc < 2; ++fc)
            #pragma unroll
            for (int ks = 0; ks < 2; ++ks)
                bq[1][fc][ks] = rdB(cur, 1, fc, ks);
        stage(nxt, tn, 1, wn * 64 + 32 + wm * 16);
        stage(nxt, tn, 1, wn * 64 + 32 + wm * 16 + 8);
        __builtin_amdgcn_s_setprio(1);
        #pragma unroll
        for (int fr = 0; fr < 4; ++fr)
            #pragma unroll
            for (int fc = 0; fc < 2; ++fc)
                #pragma unroll
                for (int ks = 0; ks < 2; ++ks)
                    acc[fr][2 + fc] = __builtin_amdgcn_mfma_f32_16x16x32_bf16(
                        af[fr][ks], bq[1][fc][ks], acc[fr][2 + fc], 0, 0, 0);
        __builtin_amdgcn_s_setprio(0);

        // ============ phase 2+3: quadrants (qr1, qc0) and (qr1, qc1) ============
        asm volatile("s_waitcnt vmcnt(6)" ::: "memory");
        __builtin_amdgcn_s_barrier();
        __builtin_amdgcn_sched_barrier(0);
        #pragma unroll
        for (int fr = 0; fr < 4; ++fr)
            #pragma unroll
            for (int ks = 0; ks < 2; ++ks)
                af[fr][ks] = rdA(cur, 1, fr, ks);
        stage(nxt, tn, 0, wm * 128 + 64 + wn * 16);
        stage(nxt, tn, 0, wm * 128 + 64 + wn * 16 + 8);
        __builtin_amdgcn_s_setprio(1);
        #pragma unroll
        for (int fr = 0; fr < 4; ++fr)
            #pragma unroll
            for (int fc = 0; fc < 2; ++fc)
                #pragma unroll
                for (int ks = 0; ks < 2; ++ks)
                    acc[4 + fr][fc] = __builtin_amdgcn_mfma_f32_16x16x32_bf16(
                        af[fr][ks], bq[0][fc][ks], acc[4 + fr][fc], 0, 0, 0);
        #pragma unroll
        for (int fr = 0; fr < 4; ++fr)
            #pragma unroll
            for (int fc = 0; fc < 2; ++fc)
                #pragma unroll
                for (int ks = 0; ks < 2; ++ks)
                    acc[4 + fr][2 + fc] = __builtin_amdgcn_mfma_f32_16x16x32_bf16(
                        af[fr][ks], bq[1][fc][ks], acc[4 + fr][2 + fc], 0, 0, 0);
        __builtin_amdgcn_s_setprio(0);
    }

    // ---- epilogue: bias + store (C layout: col = lane&15, row = kh*4 + r)
    const int sel  = nt >> 2;                       // which output (qkv) / 0
    const float* bias = (sel == 0) ? bias0 : (sel == 1) ? bias1 : bias2;
    void* outp        = (sel == 0) ? out0  : (sel == 1) ? out1  : out2;
    const int r4 = kh * 4;
    #pragma unroll
    for (int n = 0; n < 4; ++n) {
        const int c  = (nt & 3) * 256 + wn * 64 + n * 16 + l15;
        const float bb = bias[c];
        #pragma unroll
        for (int i = 0; i < 8; ++i) {
            #pragma unroll
            for (int r = 0; r < 4; ++r) {
                const int gr = row0 + wm * 128 + i * 16 + r4 + r;
                if (gr < M) {
                    const float val = acc[i][n][r] + bb;
                    if (BF16OUT) ((ushort*)outp)[(size_t)gr * DIMC + c] = f2bf(val);
                    else         ((float*)outp)[(size_t)gr * DIMC + c]  = val;
                }
            }
        }
    }
}

// ---------------------------------------------------------------------------
__global__ __launch_bounds__(256) void cvt_pad(
    const float* __restrict__ x, ushort* __restrict__ xb, int nvalid, int ntot)
{
    const int stride = gridDim.x * blockDim.x;
    for (int i = blockIdx.x * blockDim.x + threadIdx.x; i < ntot / 4; i += stride) {
        const int e = i * 4;
        ushort4 o;
        if (e < nvalid) {
            const float4 f = *(const float4*)(x + e);
            o.x = f2bf(f.x); o.y = f2bf(f.y); o.z = f2bf(f.z); o.w = f2bf(f.w);
        } else { o.x = o.y = o.z = o.w = 0; }
        *(ushort4*)(xb + e) = o;
    }
}

__global__ __launch_bounds__(256) void transpose_w4(
    const float* __restrict__ W0, const float* __restrict__ W1,
    const float* __restrict__ W2, const float* __restrict__ W3,
    ushort* __restrict__ T0, ushort* __restrict__ T1,
    ushort* __restrict__ T2, ushort* __restrict__ T3)
{
    __shared__ float tile[32][33];
    const int z = blockIdx.z;
    const float* W = (z == 0) ? W0 : (z == 1) ? W1 : (z == 2) ? W2 : W3;
    ushort*      T = (z == 0) ? T0 : (z == 1) ? T1 : (z == 2) ? T2 : T3;
    const int tx = threadIdx.x & 31;
    const int ty = threadIdx.x >> 5;
    const int n0 = blockIdx.x * 32;
    const int k0 = blockIdx.y * 32;
    #pragma unroll
    for (int i = 0; i < 32; i += 8)
        tile[ty + i][tx] = W[(size_t)(k0 + ty + i) * DIMC + n0 + tx];
    __syncthreads();
    #pragma unroll
    for (int i = 0; i < 32; i += 8)
        T[(size_t)(n0 + ty + i) * DIMC + k0 + tx] = f2bf(tile[tx][ty + i]);
}

// ---------------------------------------------------------------------------
// MFMA flash attention (unchanged from round 6 — verified passing).
// ---------------------------------------------------------------------------
__global__ __launch_bounds__(64) void attn_mfma(
    const ushort* __restrict__ qg, const ushort* __restrict__ kg,
    const ushort* __restrict__ vg, ushort* __restrict__ og,
    const int* __restrict__ lens, int B)
{
    __shared__ ushort Vt[64 * 68];   // V^T tile: Vt[d][key], row stride 68 ushorts

    const int i   = blockIdx.x;
    const int xcd = i & 7;
    const int j   = i >> 3;
    const int bh  = xcd * (B * 2) + (j >> 2);
    const int qt  = j & 3;
    const int h   = bh & 15;
    const int b   = bh >> 4;

    const int lane = threadIdx.x & 63;

    const int myl = (lane < B) ? lens[lane] : 0;
    int inc = myl;
    #pragma unroll
    for (int d = 1; d < 64; d <<= 1) {
        const int nb = __shfl_up(inc, d);
        if (lane >= d) inc += nb;
    }
    const int off = __shfl(inc, b) - __shfl(myl, b);
    const int L   = __shfl(myl, b);
    if (qt * 64 >= L) return;
    const int ntk = (L + 63) >> 6;

    const int l31 = lane & 31;
    const int hi  = lane >> 5;
    const int kp  = lane & 31;
    const int dh  = lane >> 5;

    bf16x8 qf[2][4];
    #pragma unroll
    for (int qn = 0; qn < 2; ++qn) {
        const size_t row = (size_t)(off + min(qt * 64 + qn * 32 + l31, L - 1));
        #pragma unroll
        for (int ks = 0; ks < 4; ++ks) {
            union { uint4 u4; ushort us[8]; bf16x8 v; } tmp;
            tmp.u4 = *(const uint4*)(qg + row * DIMC + h * HDIM + ks * 16 + hi * 8);
            #pragma unroll
            for (int e = 0; e < 8; ++e)
                tmp.us[e] = f2bf(bf2f(tmp.us[e]) * 0.03125f);
            qf[qn][ks] = tmp.v;
        }
    }

    f32x16 o[2][2] = {};
    float mst[2] = {-1e30f, -1e30f};
    float lst[2] = {0.f, 0.f};

    uint4 va[4], vbr[4];
    auto issueV = [&](int tt) {
        const int j0s = tt * 64;
        #pragma unroll
        for (int it = 0; it < 4; ++it) {
            const int d0 = (it * 2 + dh) * 8;
            const size_t r0 = (size_t)(off + min(j0s + 2 * kp,     L - 1));
            const size_t r1 = (size_t)(off + min(j0s + 2 * kp + 1, L - 1));
            va[it]  = *(const uint4*)(vg + r0 * DIMC + h * HDIM + d0);
            vbr[it] = *(const uint4*)(vg + r1 * DIMC + h * HDIM + d0);
        }
    };

    bf16x8 kfc[2][4], kfn[2][4];
    auto loadK = [&](int tt, bf16x8 (&kf)[2][4]) {
        const int j0s = tt * 64;
        #pragma unroll
        for (int km = 0; km < 2; ++km) {
            const size_t row = (size_t)(off + min(j0s + km * 32 + l31, L - 1));
            #pragma unroll
            for (int ks = 0; ks < 4; ++ks)
                kf[km][ks] = *(const bf16x8*)(kg + row * DIMC + h * HDIM + ks * 16 + hi * 8);
        }
    };

    issueV(0);
    loadK(0, kfc);

    for (int t = 0; t < ntk; ++t) {
        const int j0 = t * 64;

        loadK(min(t + 1, ntk - 1), kfn);

        f32x16 s[2][2] = {};
        __builtin_amdgcn_s_setprio(1);
        #pragma unroll
        for (int km = 0; km < 2; ++km)
            #pragma unroll
            for (int qn = 0; qn < 2; ++qn)
                #pragma unroll
                for (int ks = 0; ks < 4; ++ks)
                    s[km][qn] = __builtin_amdgcn_mfma_f32_32x32x16_bf16(
                        kfc[km][ks], qf[qn][ks], s[km][qn], 0, 0, 0);
        __builtin_amdgcn_s_setprio(0);

        #pragma unroll
        for (int it = 0; it < 4; ++it) {
            const int d0 = (it * 2 + dh) * 8;
            const uint a4[4] = {va[it].x,  va[it].y,  va[it].z,  va[it].w};
            const uint b4[4] = {vbr[it].x, vbr[it].y, vbr[it].z, vbr[it].w};
            #pragma unroll
            for (int jj = 0; jj < 4; ++jj) {
                const uint lo  = (a4[jj] & 0xffffu) | (b4[jj] << 16);
                const uint hi2 = (a4[jj] >> 16) | (b4[jj] & 0xffff0000u);
                *(uint*)&Vt[(d0 + 2 * jj)     * 68 + 2 * kp] = lo;
                *(uint*)&Vt[(d0 + 2 * jj + 1) * 68 + 2 * kp] = hi2;
            }
        }
        if (t + 1 < ntk) issueV(t + 1);

        const bool fullTile = (j0 + 64 <= L);
        float tmv[2];
        #pragma unroll
        for (int qn = 0; qn < 2; ++qn) {
            float tm = -1e30f;
            if (fullTile) {
                #pragma unroll
                for (int km = 0; km < 2; ++km)
                    #pragma unroll
                    for (int r = 0; r < 16; ++r)
                        tm = fmaxf(tm, s[km][qn][r]);
            } else {
                #pragma unroll
                for (int km = 0; km < 2; ++km)
                    #pragma unroll
                    for (int r = 0; r < 16; ++r) {
                        const int key = j0 + km * 32 + (r & 3) + 8 * (r >> 2) + 4 * hi;
                        float sv = s[km][qn][r];
                        sv = (key < L) ? sv : -1e30f;
                        s[km][qn][r] = sv;
                        tm = fmaxf(tm, sv);
                    }
            }
            tm = fmaxf(tm, __shfl_xor(tm, 32));
            tmv[qn] = tm;
        }

        const bool need = (tmv[0] > mst[0] + 4.f) || (tmv[1] > mst[1] + 4.f);
        if (__any(need)) {
            #pragma unroll
            for (int qn = 0; qn < 2; ++qn) {
                const float nm = fmaxf(mst[qn], tmv[qn]);
                const float corr = __expf(mst[qn] - nm);
                mst[qn] = nm;
                lst[qn] *= corr;
                #pragma unroll
                for (int dm = 0; dm < 2; ++dm)
                    #pragma unroll
                    for (int r = 0; r < 16; ++r)
                        o[dm][qn][r] *= corr;
            }
        }
        #pragma unroll
        for (int qn = 0; qn < 2; ++qn) {
            float ls = 0.f;
            #pragma unroll
            for (int km = 0; km < 2; ++km)
                #pragma unroll
                for (int r = 0; r < 16; ++r) {
                    const float p = __expf(s[km][qn][r] - mst[qn]);
                    s[km][qn][r] = p;
                    ls += p;
                }
            ls += __shfl_xor(ls, 32);
            lst[qn] += ls;
        }

        #pragma unroll
        for (int kspv = 0; kspv < 4; ++kspv) {
            const int km = kspv >> 1;
            const int sb = kspv & 1;

            bf16x8 Afr[2];
            #pragma unroll
            for (int dm = 0; dm < 2; ++dm) {
                const int d = dm * 32 + l31;
                const uint2 p0 = *(const uint2*)&Vt[d * 68 + kspv * 16 + hi * 8];
                const uint2 p1 = *(const uint2*)&Vt[d * 68 + kspv * 16 + hi * 8 + 4];
                union { uint u[4]; bf16x8 v; } aa;
                aa.u[0] = p0.x; aa.u[1] = p0.y; aa.u[2] = p1.x; aa.u[3] = p1.y;
                Afr[dm] = aa.v;
            }

            bf16x8 Bfr[2];
            #pragma unroll
            for (int qn = 0; qn < 2; ++qn) {
                const uint X0 = pkbf(s[km][qn][8 * sb + 0], s[km][qn][8 * sb + 1]);
                const uint X1 = pkbf(s[km][qn][8 * sb + 2], s[km][qn][8 * sb + 3]);
                const uint Y0 = pkbf(s[km][qn][8 * sb + 4], s[km][qn][8 * sb + 5]);
                const uint Y1 = pkbf(s[km][qn][8 * sb + 6], s[km][qn][8 * sb + 7]);
                const uint sx0 = (uint)__shfl_xor((int)X0, 32);
                const uint sx1 = (uint)__shfl_xor((int)X1, 32);
                const uint sy0 = (uint)__shfl_xor((int)Y0, 32);
                const uint sy1 = (uint)__shfl_xor((int)Y1, 32);
                union { uint u[4]; bf16x8 v; } bb;
                bb.u[0] = hi ? sy0 : X0;
                bb.u[1] = hi ? sy1 : X1;
                bb.u[2] = hi ? Y0 : sx0;
                bb.u[3] = hi ? Y1 : sx1;
                Bfr[qn] = bb.v;
            }

            __builtin_amdgcn_s_setprio(1);
            #pragma unroll
            for (int dm = 0; dm < 2; ++dm)
                #pragma unroll
                for (int qn = 0; qn < 2; ++qn)
                    o[dm][qn] = __builtin_amdgcn_mfma_f32_32x32x16_bf16(
                        Afr[dm], Bfr[qn], o[dm][qn], 0, 0, 0);
            __builtin_amdgcn_s_setprio(0);
        }

        #pragma unroll
        for (int km = 0; km < 2; ++km)
            #pragma unroll
            for (int ks = 0; ks < 4; ++ks)
                kfc[km][ks] = kfn[km][ks];
    }

    #pragma unroll
    for (int qn = 0; qn < 2; ++qn) {
        const int q = qt * 64 + qn * 32 + l31;
        if (q < L) {
            const float inv = 1.f / lst[qn];
            ushort* orow = og + (size_t)(off + q) * DIMC + h * HDIM;
            #pragma unroll
            for (int dm = 0; dm < 2; ++dm)
                #pragma unroll
                for (int bq2 = 0; bq2 < 4; ++bq2) {
                    const int r0 = 4 * bq2;
                    uint2 st;
                    st.x = pkbf(o[dm][qn][r0 + 0] * inv, o[dm][qn][r0 + 1] * inv);
                    st.y = pkbf(o[dm][qn][r0 + 2] * inv, o[dm][qn][r0 + 3] * inv);
                    *(uint2*)(orow + dm * 32 + 8 * bq2 + 4 * hi) = st;
                }
        }
    }
}

// ---------------------------------------------------------------------------
extern "C" void kernel_launch(void* const* d_in, const int* in_sizes, int n_in,
                              void* d_out, int out_size, void* d_ws, size_t ws_size,
                              hipStream_t stream)
{
    const float* x   = (const float*)d_in[0];
    const float* Wq  = (const float*)d_in[1];
    const float* bq  = (const float*)d_in[2];
    const float* Wk  = (const float*)d_in[3];
    const float* bk  = (const float*)d_in[4];
    const float* Wv  = (const float*)d_in[5];
    const float* bv  = (const float*)d_in[6];
    const float* Wu  = (const float*)d_in[7];
    const float* bu  = (const float*)d_in[8];
    const int*  lens = (const int*)d_in[9];

    const int N = in_sizes[0] / DIMC;    // 12224
    const int B = in_sizes[9];           // 64

    ushort* xb  = (ushort*)d_ws;                         // MPAD*1024 bf16
    ushort* wtq = xb  + (size_t)MPAD * DIMC;             // 3 contiguous = Wt_cat
    ushort* wtk = wtq + (size_t)DIMC * DIMC;
    ushort* wtv = wtk + (size_t)DIMC * DIMC;
    ushort* wtu = wtv + (size_t)DIMC * DIMC;
    ushort* kb  = wtu + (size_t)DIMC * DIMC;             // N*1024 bf16
    ushort* vb  = kb  + (size_t)N * DIMC;                // N*1024 bf16
    ushort* qb  = (ushort*)d_out;                        // q lives in d_out (bf16)
    ushort* ob  = xb;                                    // attn out reuses xb

    cvt_pad<<<2048, 256, 0, stream>>>(x, xb, N * DIMC, MPAD * DIMC);
    transpose_w4<<<dim3(32, 32, 4), 256, 0, stream>>>(Wq, Wk, Wv, Wu,
                                                      wtq, wtk, wtv, wtu);

    // fused QKV: Bt = wtq|wtk|wtv (3072 rows); 48 mt x 12 nt = 576 blocks
    gemm256<true><<<576, 512, 0, stream>>>(xb, wtq, bq, bk, bv,
                                           qb, kb, vb, N, 6, 48);

    attn_mfma<<<dim3(B * NHEAD * 4), dim3(64), 0, stream>>>(qb, kb, vb, ob, lens, B);

    // final: Bt = wtu (1024 rows); 48 mt x 4 nt = 192 blocks
    gemm256<false><<<192, 512, 0, stream>>>(ob, wtu, bu, bu, bu,
                                            d_out, d_out, d_out, N, 6, 48);
}

// Round 8
// 234.887 us; speedup vs baseline: 1.0772x; 1.0772x over previous
//
#include <hip/hip_runtime.h>
#include <hip/hip_bf16.h>
#include <math.h>

#define DIMC 1024
#define NHEAD 16
#define HDIM 64
#define MPAD 12288   // 12224 padded up to multiple of 256

using bf16x8 = __attribute__((ext_vector_type(8))) short;
using f32x4  = __attribute__((ext_vector_type(4))) float;
using f32x16 = __attribute__((ext_vector_type(16))) float;

__device__ inline ushort f2bf(float f) {          // round-to-nearest-even
    uint u = __float_as_uint(f);
    u += 0x7fffu + ((u >> 16) & 1u);
    return (ushort)(u >> 16);
}
__device__ inline float bf2f(ushort h) { return __uint_as_float(((uint)h) << 16); }

__device__ inline uint pkbf(float a, float b) {   // pack 2 f32 -> 2 bf16 (lo=a)
    __hip_bfloat162 t = __float22bfloat162_rn(float2{a, b});
    return *reinterpret_cast<uint*>(&t);
}

__device__ inline void gload_lds16(const ushort* g, ushort* l) {
    __builtin_amdgcn_global_load_lds(
        (const __attribute__((address_space(1))) uint*)g,
        (__attribute__((address_space(3))) uint*)l, 16, 0, 0);
}

// ---------------------------------------------------------------------------
// QKV GEMM: 256x192 tile, 3-barrier counted-vmcnt schedule.
//   out[qkv] = A[MPAD x 1024](bf16) x Wt_cat[3072 x 1024]^T + bias
// Grid 48 mt x 16 nt = 768 blocks = EXACTLY 3 rounds at 1 block/CU.
// 8 waves (2M x 4N): per-wave out 128 x 48 (8 row-frags x 3 col-frags).
// Per-wave 7 loads/K-tile, slots (issue order): A0(2) B01(2) B2(1) A1(2).
//   p0 wait vmcnt(3): retires A0,B01 -> read qr0 + cols 0-31; issue A0,B01(t+1)
//   p1 wait vmcnt(6): retires B2     -> read cols 32-47;      issue B2(t+1)
//   p2 wait vmcnt(5): retires A1     -> read qr1;             issue A1(t+1)
// Each wave waits only its own loads; s_barrier joins -> all quarters landed.
// LDS 112KB dbuf; (row&7)<<4 XOR swizzle (verified conflict-free, r7: 0).
// 192-wide tiles straddle q|k|v boundaries: per-frag output select (16 | 1024).
// ---------------------------------------------------------------------------
__global__ __launch_bounds__(512, 2) void gemm192(
    const ushort* __restrict__ A, const ushort* __restrict__ Bt,
    const float* __restrict__ bq, const float* __restrict__ bk,
    const float* __restrict__ bv,
    ushort* __restrict__ qb, ushort* __restrict__ kb, ushort* __restrict__ vb,
    int M)
{
    __shared__ ushort lds[2][(256 + 192) * 64];   // A at 0, B at 256*64 ushorts

    const int bid = blockIdx.x;
    const int xcd = bid & 7;
    const int j   = bid >> 3;                     // 0..95
    const int mt  = xcd * 6 + (j % 6);            // 0..47
    const int nt  = j / 6;                        // 0..15
    const int row0 = mt * 256;
    const int col0 = nt * 192;

    const int t512 = threadIdx.x;
    const int w    = t512 >> 6;
    const int lane = t512 & 63;
    const int wm   = w >> 2;                      // 0..1
    const int wn   = w & 3;                       // 0..3
    const int l15  = lane & 15;
    const int kh   = lane >> 4;                   // 0..3

    auto stage = [&](int buf, int kt, int mat, int relRow) {
        const int o   = relRow * 128 + lane * 16;
        const int row = o >> 7;
        const int kb_ = (o & 127) ^ ((row & 7) << 4);
        const ushort* src = (mat ? Bt + (size_t)(col0 + row) * DIMC
                                 : A  + (size_t)(row0 + row) * DIMC)
                            + kt * 64 + (kb_ >> 1);
        gload_lds16(src, &lds[buf][0] + mat * (256 * 64) + relRow * 64);
    };
    auto rdA = [&](int buf, int qr, int fr, int ks) -> bf16x8 {
        const int row = wm * 128 + qr * 64 + fr * 16 + l15;
        const int ad  = (row * 128 + ks * 64 + kh * 16) ^ ((row & 7) << 4);
        return *(const bf16x8*)(&lds[buf][0] + (ad >> 1));
    };
    auto rdB = [&](int buf, int n, int ks) -> bf16x8 {
        const int row = wn * 48 + n * 16 + l15;
        const int ad  = (row * 128 + ks * 64 + kh * 16) ^ ((row & 7) << 4);
        return *(const bf16x8*)(&lds[buf][256 * 64] + (ad >> 1));
    };

    f32x4 acc[8][3] = {};
    bf16x8 af[4][2];        // current row-half frags
    bf16x8 bf[3][2];        // all 3 col-frags stay live

    // prologue: tile 0 -> buf 0, slot order A0 B01 B2 A1
    stage(0, 0, 0, wm * 128 + wn * 16);
    stage(0, 0, 0, wm * 128 + wn * 16 + 8);
    stage(0, 0, 1, wn * 48 + wm * 16);
    stage(0, 0, 1, wn * 48 + wm * 16 + 8);
    stage(0, 0, 1, wn * 48 + 32 + wm * 8);
    stage(0, 0, 0, wm * 128 + 64 + wn * 16);
    stage(0, 0, 0, wm * 128 + 64 + wn * 16 + 8);

    const int NT = DIMC / 64;    // 16
    for (int t = 0; t < NT; ++t) {
        const int cur = t & 1;
        const int nxt = cur ^ 1;
        const int tn  = (t + 1 < NT) ? (t + 1) : (NT - 1);   // last iter: dead restage

        // ---------------- phase 0: qr0 x cols 0-31 ----------------
        asm volatile("s_waitcnt vmcnt(3)" ::: "memory");
        __builtin_amdgcn_s_barrier();
        __builtin_amdgcn_sched_barrier(0);
        #pragma unroll
        for (int fr = 0; fr < 4; ++fr)
            #pragma unroll
            for (int ks = 0; ks < 2; ++ks)
                af[fr][ks] = rdA(cur, 0, fr, ks);
        #pragma unroll
        for (int n = 0; n < 2; ++n)
            #pragma unroll
            for (int ks = 0; ks < 2; ++ks)
                bf[n][ks] = rdB(cur, n, ks);
        stage(nxt, tn, 0, wm * 128 + wn * 16);
        stage(nxt, tn, 0, wm * 128 + wn * 16 + 8);
        stage(nxt, tn, 1, wn * 48 + wm * 16);
        stage(nxt, tn, 1, wn * 48 + wm * 16 + 8);
        __builtin_amdgcn_s_setprio(1);
        #pragma unroll
        for (int fr = 0; fr < 4; ++fr)
            #pragma unroll
            for (int n = 0; n < 2; ++n)
                #pragma unroll
                for (int ks = 0; ks < 2; ++ks)
                    acc[fr][n] = __builtin_amdgcn_mfma_f32_16x16x32_bf16(
                        af[fr][ks], bf[n][ks], acc[fr][n], 0, 0, 0);
        __builtin_amdgcn_s_setprio(0);

        // ---------------- phase 1: qr0 x cols 32-47 ----------------
        asm volatile("s_waitcnt vmcnt(6)" ::: "memory");
        __builtin_amdgcn_s_barrier();
        __builtin_amdgcn_sched_barrier(0);
        #pragma unroll
        for (int ks = 0; ks < 2; ++ks)
            bf[2][ks] = rdB(cur, 2, ks);
        stage(nxt, tn, 1, wn * 48 + 32 + wm * 8);
        __builtin_amdgcn_s_setprio(1);
        #pragma unroll
        for (int fr = 0; fr < 4; ++fr)
            #pragma unroll
            for (int ks = 0; ks < 2; ++ks)
                acc[fr][2] = __builtin_amdgcn_mfma_f32_16x16x32_bf16(
                    af[fr][ks], bf[2][ks], acc[fr][2], 0, 0, 0);
        __builtin_amdgcn_s_setprio(0);

        // ---------------- phase 2: qr1 x all 48 cols ----------------
        asm volatile("s_waitcnt vmcnt(5)" ::: "memory");
        __builtin_amdgcn_s_barrier();
        __builtin_amdgcn_sched_barrier(0);
        #pragma unroll
        for (int fr = 0; fr < 4; ++fr)
            #pragma unroll
            for (int ks = 0; ks < 2; ++ks)
                af[fr][ks] = rdA(cur, 1, fr, ks);
        stage(nxt, tn, 0, wm * 128 + 64 + wn * 16);
        stage(nxt, tn, 0, wm * 128 + 64 + wn * 16 + 8);
        __builtin_amdgcn_s_setprio(1);
        #pragma unroll
        for (int fr = 0; fr < 4; ++fr)
            #pragma unroll
            for (int n = 0; n < 3; ++n)
                #pragma unroll
                for (int ks = 0; ks < 2; ++ks)
                    acc[4 + fr][n] = __builtin_amdgcn_mfma_f32_16x16x32_bf16(
                        af[fr][ks], bf[n][ks], acc[4 + fr][n], 0, 0, 0);
        __builtin_amdgcn_s_setprio(0);
    }

    // epilogue: per-frag q/k/v select (frags never straddle 1024 boundaries)
    #pragma unroll
    for (int n = 0; n < 3; ++n) {
        const int cg = col0 + wn * 48 + n * 16 + l15;
        const int s  = cg >> 10;
        const int cb = cg & 1023;
        const float bb = ((s == 0) ? bq : (s == 1) ? bk : bv)[cb];
        ushort* op     = (s == 0) ? qb : (s == 1) ? kb : vb;
        #pragma unroll
        for (int i = 0; i < 8; ++i) {
            #pragma unroll
            for (int r = 0; r < 4; ++r) {
                const int gr = row0 + wm * 128 + i * 16 + kh * 4 + r;
                if (gr < M)
                    op[(size_t)gr * DIMC + cb] = f2bf(acc[i][n][r] + bb);
            }
        }
    }
}

// ---------------------------------------------------------------------------
// Final GEMM (fp32 out): 256x256 4-phase counted-vmcnt (round-7 kernel,
// verified).  Grid 192 blocks = 1 round.
// ---------------------------------------------------------------------------
__global__ __launch_bounds__(512, 2) void gemm256f(
    const ushort* __restrict__ A, const ushort* __restrict__ Bt,
    const float* __restrict__ bias, float* __restrict__ C, int M)
{
    __shared__ ushort lds[2][2][256 * 64];

    const int bid = blockIdx.x;
    const int xcd = bid & 7;
    const int j   = bid >> 3;
    const int mt  = xcd * 6 + (j % 6);
    const int nt  = j / 6;                        // 0..3
    const int row0 = mt * 256;
    const int col0 = nt * 256;

    const int t512 = threadIdx.x;
    const int w    = t512 >> 6;
    const int lane = t512 & 63;
    const int wm   = w >> 2;
    const int wn   = w & 3;
    const int l15  = lane & 15;
    const int kh   = lane >> 4;

    auto stage = [&](int buf, int kt, int mat, int relRow) {
        const int o   = relRow * 128 + lane * 16;
        const int row = o >> 7;
        const int kb_ = (o & 127) ^ ((row & 7) << 4);
        const ushort* src = (mat ? Bt + (size_t)(col0 + row) * DIMC
                                 : A  + (size_t)(row0 + row) * DIMC)
                            + kt * 64 + (kb_ >> 1);
        gload_lds16(src, &lds[buf][mat][0] + relRow * 64);
    };
    auto rdA = [&](int buf, int qr, int fr, int ks) -> bf16x8 {
        const int row = wm * 128 + qr * 64 + fr * 16 + l15;
        const int ad  = (row * 128 + ks * 64 + kh * 16) ^ ((row & 7) << 4);
        return *(const bf16x8*)(&lds[buf][0][0] + (ad >> 1));
    };
    auto rdB = [&](int buf, int qc, int fc, int ks) -> bf16x8 {
        const int row = wn * 64 + qc * 32 + fc * 16 + l15;
        const int ad  = (row * 128 + ks * 64 + kh * 16) ^ ((row & 7) << 4);
        return *(const bf16x8*)(&lds[buf][1][0] + (ad >> 1));
    };

    f32x4 acc[8][4] = {};
    bf16x8 af[4][2];
    bf16x8 bq2[2][2][2];

    stage(0, 0, 0, wm * 128 + wn * 16);
    stage(0, 0, 0, wm * 128 + wn * 16 + 8);
    stage(0, 0, 1, wn * 64 + wm * 16);
    stage(0, 0, 1, wn * 64 + wm * 16 + 8);
    stage(0, 0, 1, wn * 64 + 32 + wm * 16);
    stage(0, 0, 1, wn * 64 + 32 + wm * 16 + 8);
    stage(0, 0, 0, wm * 128 + 64 + wn * 16);
    stage(0, 0, 0, wm * 128 + 64 + wn * 16 + 8);

    const int NT = DIMC / 64;
    for (int t = 0; t < NT; ++t) {
        const int cur = t & 1;
        const int nxt = cur ^ 1;
        const int tn  = (t + 1 < NT) ? (t + 1) : (NT - 1);

        asm volatile("s_waitcnt vmcnt(4)" ::: "memory");
        __builtin_amdgcn_s_barrier();
        __builtin_amdgcn_sched_barrier(0);
        #pragma unroll
        for (int fr = 0; fr < 4; ++fr)
            #pragma unroll
            for (int ks = 0; ks < 2; ++ks)
                af[fr][ks] = rdA(cur, 0, fr, ks);
        #pragma unroll
        for (int fc = 0; fc < 2; ++fc)
            #pragma unroll
            for (int ks = 0; ks < 2; ++ks)
                bq2[0][fc][ks] = rdB(cur, 0, fc, ks);
        stage(nxt, tn, 0, wm * 128 + wn * 16);
        stage(nxt, tn, 0, wm * 128 + wn * 16 + 8);
        stage(nxt, tn, 1, wn * 64 + wm * 16);
        stage(nxt, tn, 1, wn * 64 + wm * 16 + 8);
        __builtin_amdgcn_s_setprio(1);
        #pragma unroll
        for (int fr = 0; fr < 4; ++fr)
            #pragma unroll
            for (int fc = 0; fc < 2; ++fc)
                #pragma unroll
                for (int ks = 0; ks < 2; ++ks)
                    acc[fr][fc] = __builtin_amdgcn_mfma_f32_16x16x32_bf16(
                        af[fr][ks], bq2[0][fc][ks], acc[fr][fc], 0, 0, 0);
        __builtin_amdgcn_s_setprio(0);

        asm volatile("s_waitcnt vmcnt(6)" ::: "memory");
        __builtin_amdgcn_s_barrier();
        __builtin_amdgcn_sched_barrier(0);
        #pragma unroll
        for (int fc = 0; fc < 2; ++fc)
            #pragma unroll
            for (int ks = 0; ks < 2; ++ks)
                bq2[1][fc][ks] = rdB(cur, 1, fc, ks);
        stage(nxt, tn, 1, wn * 64 + 32 + wm * 16);
        stage(nxt, tn, 1, wn * 64 + 32 + wm * 16 + 8);
        __builtin_amdgcn_s_setprio(1);
        #pragma unroll
        for (int fr = 0; fr < 4; ++fr)
            #pragma unroll
            for (int fc = 0; fc < 2; ++fc)
                #pragma unroll
                for (int ks = 0; ks < 2; ++ks)
                    acc[fr][2 + fc] = __builtin_amdgcn_mfma_f32_16x16x32_bf16(
                        af[fr][ks], bq2[1][fc][ks], acc[fr][2 + fc], 0, 0, 0);
        __builtin_amdgcn_s_setprio(0);

        asm volatile("s_waitcnt vmcnt(6)" ::: "memory");
        __builtin_amdgcn_s_barrier();
        __builtin_amdgcn_sched_barrier(0);
        #pragma unroll
        for (int fr = 0; fr < 4; ++fr)
            #pragma unroll
            for (int ks = 0; ks < 2; ++ks)
                af[fr][ks] = rdA(cur, 1, fr, ks);
        stage(nxt, tn, 0, wm * 128 + 64 + wn * 16);
        stage(nxt, tn, 0, wm * 128 + 64 + wn * 16 + 8);
        __builtin_amdgcn_s_setprio(1);
        #pragma unroll
        for (int fr = 0; fr < 4; ++fr)
            #pragma unroll
            for (int fc = 0; fc < 2; ++fc)
                #pragma unroll
                for (int ks = 0; ks < 2; ++ks)
                    acc[4 + fr][fc] = __builtin_amdgcn_mfma_f32_16x16x32_bf16(
                        af[fr][ks], bq2[0][fc][ks], acc[4 + fr][fc], 0, 0, 0);
        #pragma unroll
        for (int fr = 0; fr < 4; ++fr)
            #pragma unroll
            for (int fc = 0; fc < 2; ++fc)
                #pragma unroll
                for (int ks = 0; ks < 2; ++ks)
                    acc[4 + fr][2 + fc] = __builtin_amdgcn_mfma_f32_16x16x32_bf16(
                        af[fr][ks], bq2[1][fc][ks], acc[4 + fr][2 + fc], 0, 0, 0);
        __builtin_amdgcn_s_setprio(0);
    }

    #pragma unroll
    for (int n = 0; n < 4; ++n) {
        const int c  = col0 + wn * 64 + n * 16 + l15;
        const float bb = bias[c];
        #pragma unroll
        for (int i = 0; i < 8; ++i) {
            #pragma unroll
            for (int r = 0; r < 4; ++r) {
                const int gr = row0 + wm * 128 + i * 16 + kh * 4 + r;
                if (gr < M)
                    C[(size_t)gr * DIMC + c] = acc[i][n][r] + bb;
            }
        }
    }
}

// ---------------------------------------------------------------------------
__global__ __launch_bounds__(256) void cvt_pad(
    const float* __restrict__ x, ushort* __restrict__ xb, int nvalid, int ntot)
{
    const int stride = gridDim.x * blockDim.x;
    for (int i = blockIdx.x * blockDim.x + threadIdx.x; i < ntot / 4; i += stride) {
        const int e = i * 4;
        ushort4 o;
        if (e < nvalid) {
            const float4 f = *(const float4*)(x + e);
            o.x = f2bf(f.x); o.y = f2bf(f.y); o.z = f2bf(f.z); o.w = f2bf(f.w);
        } else { o.x = o.y = o.z = o.w = 0; }
        *(ushort4*)(xb + e) = o;
    }
}

__global__ __launch_bounds__(256) void transpose_w4(
    const float* __restrict__ W0, const float* __restrict__ W1,
    const float* __restrict__ W2, const float* __restrict__ W3,
    ushort* __restrict__ T0, ushort* __restrict__ T1,
    ushort* __restrict__ T2, ushort* __restrict__ T3)
{
    __shared__ float tile[32][33];
    const int z = blockIdx.z;
    const float* W = (z == 0) ? W0 : (z == 1) ? W1 : (z == 2) ? W2 : W3;
    ushort*      T = (z == 0) ? T0 : (z == 1) ? T1 : (z == 2) ? T2 : T3;
    const int tx = threadIdx.x & 31;
    const int ty = threadIdx.x >> 5;
    const int n0 = blockIdx.x * 32;
    const int k0 = blockIdx.y * 32;
    #pragma unroll
    for (int i = 0; i < 32; i += 8)
        tile[ty + i][tx] = W[(size_t)(k0 + ty + i) * DIMC + n0 + tx];
    __syncthreads();
    #pragma unroll
    for (int i = 0; i < 32; i += 8)
        T[(size_t)(n0 + ty + i) * DIMC + k0 + tx] = f2bf(tile[tx][ty + i]);
}

// ---------------------------------------------------------------------------
// MFMA flash attention (unchanged from round 6 — verified passing).
// ---------------------------------------------------------------------------
__global__ __launch_bounds__(64) void attn_mfma(
    const ushort* __restrict__ qg, const ushort* __restrict__ kg,
    const ushort* __restrict__ vg, ushort* __restrict__ og,
    const int* __restrict__ lens, int B)
{
    __shared__ ushort Vt[64 * 68];

    const int i   = blockIdx.x;
    const int xcd = i & 7;
    const int j   = i >> 3;
    const int bh  = xcd * (B * 2) + (j >> 2);
    const int qt  = j & 3;
    const int h   = bh & 15;
    const int b   = bh >> 4;

    const int lane = threadIdx.x & 63;

    const int myl = (lane < B) ? lens[lane] : 0;
    int inc = myl;
    #pragma unroll
    for (int d = 1; d < 64; d <<= 1) {
        const int nb = __shfl_up(inc, d);
        if (lane >= d) inc += nb;
    }
    const int off = __shfl(inc, b) - __shfl(myl, b);
    const int L   = __shfl(myl, b);
    if (qt * 64 >= L) return;
    const int ntk = (L + 63) >> 6;

    const int l31 = lane & 31;
    const int hi  = lane >> 5;
    const int kp  = lane & 31;
    const int dh  = lane >> 5;

    bf16x8 qf[2][4];
    #pragma unroll
    for (int qn = 0; qn < 2; ++qn) {
        const size_t row = (size_t)(off + min(qt * 64 + qn * 32 + l31, L - 1));
        #pragma unroll
        for (int ks = 0; ks < 4; ++ks) {
            union { uint4 u4; ushort us[8]; bf16x8 v; } tmp;
            tmp.u4 = *(const uint4*)(qg + row * DIMC + h * HDIM + ks * 16 + hi * 8);
            #pragma unroll
            for (int e = 0; e < 8; ++e)
                tmp.us[e] = f2bf(bf2f(tmp.us[e]) * 0.03125f);
            qf[qn][ks] = tmp.v;
        }
    }

    f32x16 o[2][2] = {};
    float mst[2] = {-1e30f, -1e30f};
    float lst[2] = {0.f, 0.f};

    uint4 va[4], vbr[4];
    auto issueV = [&](int tt) {
        const int j0s = tt * 64;
        #pragma unroll
        for (int it = 0; it < 4; ++it) {
            const int d0 = (it * 2 + dh) * 8;
            const size_t r0 = (size_t)(off + min(j0s + 2 * kp,     L - 1));
            const size_t r1 = (size_t)(off + min(j0s + 2 * kp + 1, L - 1));
            va[it]  = *(const uint4*)(vg + r0 * DIMC + h * HDIM + d0);
            vbr[it] = *(const uint4*)(vg + r1 * DIMC + h * HDIM + d0);
        }
    };

    bf16x8 kfc[2][4], kfn[2][4];
    auto loadK = [&](int tt, bf16x8 (&kf)[2][4]) {
        const int j0s = tt * 64;
        #pragma unroll
        for (int km = 0; km < 2; ++km) {
            const size_t row = (size_t)(off + min(j0s + km * 32 + l31, L - 1));
            #pragma unroll
            for (int ks = 0; ks < 4; ++ks)
                kf[km][ks] = *(const bf16x8*)(kg + row * DIMC + h * HDIM + ks * 16 + hi * 8);
        }
    };

    issueV(0);
    loadK(0, kfc);

    for (int t = 0; t < ntk; ++t) {
        const int j0 = t * 64;

        loadK(min(t + 1, ntk - 1), kfn);

        f32x16 s[2][2] = {};
        __builtin_amdgcn_s_setprio(1);
        #pragma unroll
        for (int km = 0; km < 2; ++km)
            #pragma unroll
            for (int qn = 0; qn < 2; ++qn)
                #pragma unroll
                for (int ks = 0; ks < 4; ++ks)
                    s[km][qn] = __builtin_amdgcn_mfma_f32_32x32x16_bf16(
                        kfc[km][ks], qf[qn][ks], s[km][qn], 0, 0, 0);
        __builtin_amdgcn_s_setprio(0);

        #pragma unroll
        for (int it = 0; it < 4; ++it) {
            const int d0 = (it * 2 + dh) * 8;
            const uint a4[4] = {va[it].x,  va[it].y,  va[it].z,  va[it].w};
            const uint b4[4] = {vbr[it].x, vbr[it].y, vbr[it].z, vbr[it].w};
            #pragma unroll
            for (int jj = 0; jj < 4; ++jj) {
                const uint lo  = (a4[jj] & 0xffffu) | (b4[jj] << 16);
                const uint hi2 = (a4[jj] >> 16) | (b4[jj] & 0xffff0000u);
                *(uint*)&Vt[(d0 + 2 * jj)     * 68 + 2 * kp] = lo;
                *(uint*)&Vt[(d0 + 2 * jj + 1) * 68 + 2 * kp] = hi2;
            }
        }
        if (t + 1 < ntk) issueV(t + 1);

        const bool fullTile = (j0 + 64 <= L);
        float tmv[2];
        #pragma unroll
        for (int qn = 0; qn < 2; ++qn) {
            float tm = -1e30f;
            if (fullTile) {
                #pragma unroll
                for (int km = 0; km < 2; ++km)
                    #pragma unroll
                    for (int r = 0; r < 16; ++r)
                        tm = fmaxf(tm, s[km][qn][r]);
            } else {
                #pragma unroll
                for (int km = 0; km < 2; ++km)
                    #pragma unroll
                    for (int r = 0; r < 16; ++r) {
                        const int key = j0 + km * 32 + (r & 3) + 8 * (r >> 2) + 4 * hi;
                        float sv = s[km][qn][r];
                        sv = (key < L) ? sv : -1e30f;
                        s[km][qn][r] = sv;
                        tm = fmaxf(tm, sv);
                    }
            }
            tm = fmaxf(tm, __shfl_xor(tm, 32));
            tmv[qn] = tm;
        }

        const bool need = (tmv[0] > mst[0] + 4.f) || (tmv[1] > mst[1] + 4.f);
        if (__any(need)) {
            #pragma unroll
            for (int qn = 0; qn < 2; ++qn) {
                const float nm = fmaxf(mst[qn], tmv[qn]);
                const float corr = __expf(mst[qn] - nm);
                mst[qn] = nm;
                lst[qn] *= corr;
                #pragma unroll
                for (int dm = 0; dm < 2; ++dm)
                    #pragma unroll
                    for (int r = 0; r < 16; ++r)
                        o[dm][qn][r] *= corr;
            }
        }
        #pragma unroll
        for (int qn = 0; qn < 2; ++qn) {
            float ls = 0.f;
            #pragma unroll
            for (int km = 0; km < 2; ++km)
                #pragma unroll
                for (int r = 0; r < 16; ++r) {
                    const float p = __expf(s[km][qn][r] - mst[qn]);
                    s[km][qn][r] = p;
                    ls += p;
                }
            ls += __shfl_xor(ls, 32);
            lst[qn] += ls;
        }

        #pragma unroll
        for (int kspv = 0; kspv < 4; ++kspv) {
            const int km = kspv >> 1;
            const int sb = kspv & 1;

            bf16x8 Afr[2];
            #pragma unroll
            for (int dm = 0; dm < 2; ++dm) {
                const int d = dm * 32 + l31;
                const uint2 p0 = *(const uint2*)&Vt[d * 68 + kspv * 16 + hi * 8];
                const uint2 p1 = *(const uint2*)&Vt[d * 68 + kspv * 16 + hi * 8 + 4];
                union { uint u[4]; bf16x8 v; } aa;
                aa.u[0] = p0.x; aa.u[1] = p0.y; aa.u[2] = p1.x; aa.u[3] = p1.y;
                Afr[dm] = aa.v;
            }

            bf16x8 Bfr[2];
            #pragma unroll
            for (int qn = 0; qn < 2; ++qn) {
                const uint X0 = pkbf(s[km][qn][8 * sb + 0], s[km][qn][8 * sb + 1]);
                const uint X1 = pkbf(s[km][qn][8 * sb + 2], s[km][qn][8 * sb + 3]);
                const uint Y0 = pkbf(s[km][qn][8 * sb + 4], s[km][qn][8 * sb + 5]);
                const uint Y1 = pkbf(s[km][qn][8 * sb + 6], s[km][qn][8 * sb + 7]);
                const uint sx0 = (uint)__shfl_xor((int)X0, 32);
                const uint sx1 = (uint)__shfl_xor((int)X1, 32);
                const uint sy0 = (uint)__shfl_xor((int)Y0, 32);
                const uint sy1 = (uint)__shfl_xor((int)Y1, 32);
                union { uint u[4]; bf16x8 v; } bb;
                bb.u[0] = hi ? sy0 : X0;
                bb.u[1] = hi ? sy1 : X1;
                bb.u[2] = hi ? Y0 : sx0;
                bb.u[3] = hi ? Y1 : sx1;
                Bfr[qn] = bb.v;
            }

            __builtin_amdgcn_s_setprio(1);
            #pragma unroll
            for (int dm = 0; dm < 2; ++dm)
                #pragma unroll
                for (int qn = 0; qn < 2; ++qn)
                    o[dm][qn] = __builtin_amdgcn_mfma_f32_32x32x16_bf16(
                        Afr[dm], Bfr[qn], o[dm][qn], 0, 0, 0);
            __builtin_amdgcn_s_setprio(0);
        }

        #pragma unroll
        for (int km = 0; km < 2; ++km)
            #pragma unroll
            for (int ks = 0; ks < 4; ++ks)
                kfc[km][ks] = kfn[km][ks];
    }

    #pragma unroll
    for (int qn = 0; qn < 2; ++qn) {
        const int q = qt * 64 + qn * 32 + l31;
        if (q < L) {
            const float inv = 1.f / lst[qn];
            ushort* orow = og + (size_t)(off + q) * DIMC + h * HDIM;
            #pragma unroll
            for (int dm = 0; dm < 2; ++dm)
                #pragma unroll
                for (int bq2 = 0; bq2 < 4; ++bq2) {
                    const int r0 = 4 * bq2;
                    uint2 st;
                    st.x = pkbf(o[dm][qn][r0 + 0] * inv, o[dm][qn][r0 + 1] * inv);
                    st.y = pkbf(o[dm][qn][r0 + 2] * inv, o[dm][qn][r0 + 3] * inv);
                    *(uint2*)(orow + dm * 32 + 8 * bq2 + 4 * hi) = st;
                }
        }
    }
}

// ---------------------------------------------------------------------------
extern "C" void kernel_launch(void* const* d_in, const int* in_sizes, int n_in,
                              void* d_out, int out_size, void* d_ws, size_t ws_size,
                              hipStream_t stream)
{
    const float* x   = (const float*)d_in[0];
    const float* Wq  = (const float*)d_in[1];
    const float* bq  = (const float*)d_in[2];
    const float* Wk  = (const float*)d_in[3];
    const float* bk  = (const float*)d_in[4];
    const float* Wv  = (const float*)d_in[5];
    const float* bv  = (const float*)d_in[6];
    const float* Wu  = (const float*)d_in[7];
    const float* bu  = (const float*)d_in[8];
    const int*  lens = (const int*)d_in[9];

    const int N = in_sizes[0] / DIMC;    // 12224
    const int B = in_sizes[9];           // 64

    ushort* xb  = (ushort*)d_ws;                         // MPAD*1024 bf16
    ushort* wtq = xb  + (size_t)MPAD * DIMC;             // 3 contiguous = Wt_cat
    ushort* wtk = wtq + (size_t)DIMC * DIMC;
    ushort* wtv = wtk + (size_t)DIMC * DIMC;
    ushort* wtu = wtv + (size_t)DIMC * DIMC;
    ushort* kb  = wtu + (size_t)DIMC * DIMC;             // N*1024 bf16
    ushort* vb  = kb  + (size_t)N * DIMC;                // N*1024 bf16
    ushort* qb  = (ushort*)d_out;                        // q lives in d_out (bf16)
    ushort* ob  = xb;                                    // attn out reuses xb

    cvt_pad<<<2048, 256, 0, stream>>>(x, xb, N * DIMC, MPAD * DIMC);
    transpose_w4<<<dim3(32, 32, 4), 256, 0, stream>>>(Wq, Wk, Wv, Wu,
                                                      wtq, wtk, wtv, wtu);

    // fused QKV: 48 mt x 16 nt = 768 blocks = 3 exact rounds
    gemm192<<<768, 512, 0, stream>>>(xb, wtq, bq, bk, bv, qb, kb, vb, N);

    attn_mfma<<<dim3(B * NHEAD * 4), dim3(64), 0, stream>>>(qb, kb, vb, ob, lens, B);

    // final: 48 mt x 4 nt = 192 blocks = 1 round
    gemm256f<<<192, 512, 0, stream>>>(ob, wtu, bu, (float*)d_out, N);
}

// Round 11
// 228.953 us; speedup vs baseline: 1.1051x; 1.0259x over previous
//
#include <hip/hip_runtime.h>
#include <hip/hip_bf16.h>
#include <math.h>

#define DIMC 1024
#define NHEAD 16
#define HDIM 64
#define MPAD 12288   // 12224 padded up to multiple of 256 (and 192: 64*192)

using bf16x8 = __attribute__((ext_vector_type(8))) short;
using f32x4  = __attribute__((ext_vector_type(4))) float;
using f32x16 = __attribute__((ext_vector_type(16))) float;

__device__ inline ushort f2bf(float f) {          // round-to-nearest-even
    uint u = __float_as_uint(f);
    u += 0x7fffu + ((u >> 16) & 1u);
    return (ushort)(u >> 16);
}
__device__ inline float bf2f(ushort h) { return __uint_as_float(((uint)h) << 16); }

__device__ inline uint pkbf(float a, float b) {   // pack 2 f32 -> 2 bf16 (lo=a)
    __hip_bfloat162 t = __float22bfloat162_rn(float2{a, b});
    return *reinterpret_cast<uint*>(&t);
}

__device__ inline void gload_lds16(const ushort* g, ushort* l) {
    __builtin_amdgcn_global_load_lds(
        (const __attribute__((address_space(1))) uint*)g,
        (__attribute__((address_space(3))) uint*)l, 16, 0, 0);
}

// ---------------------------------------------------------------------------
// QKV GEMM: 256x192 tile, 2-phase counted-vmcnt schedule.
// Grid 48 mt x 16 nt = 768 blocks = 3 exact rounds at 1 block/CU.
// 8 waves (2M x 4N): per-wave out 128 x 48.
// Per-wave 7 loads/K-tile, slots (issue order): A0(2) B01(2) B2(1) A1(2).
//   p0 wait vmcnt(2): retires A0,B01,B2 -> read qr0 + ALL 48 cols; issue 5
//   p1 wait vmcnt(5): retires A1        -> read qr1;               issue A1
// 2 barriers/K-tile.  LDS 112KB dbuf; (row&7)<<4 XOR swizzle (verified 0
// conflicts in r7/r8).
// ---------------------------------------------------------------------------
__global__ __launch_bounds__(512, 2) void gemm192(
    const ushort* __restrict__ A, const ushort* __restrict__ Bt,
    const float* __restrict__ bq, const float* __restrict__ bk,
    const float* __restrict__ bv,
    ushort* __restrict__ qb, ushort* __restrict__ kb, ushort* __restrict__ vb,
    int M)
{
    __shared__ ushort lds[2][(256 + 192) * 64];   // A at 0, B at 256*64 ushorts

    const int bid = blockIdx.x;
    const int xcd = bid & 7;
    const int j   = bid >> 3;                     // 0..95
    const int mt  = xcd * 6 + (j % 6);            // 0..47
    const int nt  = j / 6;                        // 0..15
    const int row0 = mt * 256;
    const int col0 = nt * 192;

    const int t512 = threadIdx.x;
    const int w    = t512 >> 6;
    const int lane = t512 & 63;
    const int wm   = w >> 2;                      // 0..1
    const int wn   = w & 3;                       // 0..3
    const int l15  = lane & 15;
    const int kh   = lane >> 4;                   // 0..3

    auto stage = [&](int buf, int kt, int mat, int relRow) {
        const int o   = relRow * 128 + lane * 16;
        const int row = o >> 7;
        const int kb_ = (o & 127) ^ ((row & 7) << 4);
        const ushort* src = (mat ? Bt + (size_t)(col0 + row) * DIMC
                                 : A  + (size_t)(row0 + row) * DIMC)
                            + kt * 64 + (kb_ >> 1);
        gload_lds16(src, &lds[buf][0] + mat * (256 * 64) + relRow * 64);
    };
    auto rdA = [&](int buf, int qr, int fr, int ks) -> bf16x8 {
        const int row = wm * 128 + qr * 64 + fr * 16 + l15;
        const int ad  = (row * 128 + ks * 64 + kh * 16) ^ ((row & 7) << 4);
        return *(const bf16x8*)(&lds[buf][0] + (ad >> 1));
    };
    auto rdB = [&](int buf, int n, int ks) -> bf16x8 {
        const int row = wn * 48 + n * 16 + l15;
        const int ad  = (row * 128 + ks * 64 + kh * 16) ^ ((row & 7) << 4);
        return *(const bf16x8*)(&lds[buf][256 * 64] + (ad >> 1));
    };

    f32x4 acc[8][3] = {};
    bf16x8 af[4][2];        // current row-half frags
    bf16x8 bf[3][2];        // all 3 col-frags, read once per K-tile

    // prologue: tile 0 -> buf 0, slot order A0 B01 B2 A1
    stage(0, 0, 0, wm * 128 + wn * 16);
    stage(0, 0, 0, wm * 128 + wn * 16 + 8);
    stage(0, 0, 1, wn * 48 + wm * 16);
    stage(0, 0, 1, wn * 48 + wm * 16 + 8);
    stage(0, 0, 1, wn * 48 + 32 + wm * 8);
    stage(0, 0, 0, wm * 128 + 64 + wn * 16);
    stage(0, 0, 0, wm * 128 + 64 + wn * 16 + 8);

    const int NT = DIMC / 64;    // 16
    for (int t = 0; t < NT; ++t) {
        const int cur = t & 1;
        const int nxt = cur ^ 1;
        const int tn  = (t + 1 < NT) ? (t + 1) : (NT - 1);   // last iter: dead restage

        // -------- phase 0: qr0 x all 48 cols --------
        asm volatile("s_waitcnt vmcnt(2)" ::: "memory");
        __builtin_amdgcn_s_barrier();
        __builtin_amdgcn_sched_barrier(0);
        #pragma unroll
        for (int fr = 0; fr < 4; ++fr)
            #pragma unroll
            for (int ks = 0; ks < 2; ++ks)
                af[fr][ks] = rdA(cur, 0, fr, ks);
        #pragma unroll
        for (int n = 0; n < 3; ++n)
            #pragma unroll
            for (int ks = 0; ks < 2; ++ks)
                bf[n][ks] = rdB(cur, n, ks);
        stage(nxt, tn, 0, wm * 128 + wn * 16);
        stage(nxt, tn, 0, wm * 128 + wn * 16 + 8);
        stage(nxt, tn, 1, wn * 48 + wm * 16);
        stage(nxt, tn, 1, wn * 48 + wm * 16 + 8);
        stage(nxt, tn, 1, wn * 48 + 32 + wm * 8);
        __builtin_amdgcn_s_setprio(1);
        #pragma unroll
        for (int fr = 0; fr < 4; ++fr)
            #pragma unroll
            for (int n = 0; n < 3; ++n)
                #pragma unroll
                for (int ks = 0; ks < 2; ++ks)
                    acc[fr][n] = __builtin_amdgcn_mfma_f32_16x16x32_bf16(
                        af[fr][ks], bf[n][ks], acc[fr][n], 0, 0, 0);
        __builtin_amdgcn_s_setprio(0);

        // -------- phase 1: qr1 x all 48 cols --------
        asm volatile("s_waitcnt vmcnt(5)" ::: "memory");
        __builtin_amdgcn_s_barrier();
        __builtin_amdgcn_sched_barrier(0);
        #pragma unroll
        for (int fr = 0; fr < 4; ++fr)
            #pragma unroll
            for (int ks = 0; ks < 2; ++ks)
                af[fr][ks] = rdA(cur, 1, fr, ks);
        stage(nxt, tn, 0, wm * 128 + 64 + wn * 16);
        stage(nxt, tn, 0, wm * 128 + 64 + wn * 16 + 8);
        __builtin_amdgcn_s_setprio(1);
        #pragma unroll
        for (int fr = 0; fr < 4; ++fr)
            #pragma unroll
            for (int n = 0; n < 3; ++n)
                #pragma unroll
                for (int ks = 0; ks < 2; ++ks)
                    acc[4 + fr][n] = __builtin_amdgcn_mfma_f32_16x16x32_bf16(
                        af[fr][ks], bf[n][ks], acc[4 + fr][n], 0, 0, 0);
        __builtin_amdgcn_s_setprio(0);
    }

    // epilogue: per-frag q/k/v select (frags never straddle 1024 boundaries)
    #pragma unroll
    for (int n = 0; n < 3; ++n) {
        const int cg = col0 + wn * 48 + n * 16 + l15;
        const int s  = cg >> 10;
        const int cb = cg & 1023;
        const float bb = ((s == 0) ? bq : (s == 1) ? bk : bv)[cb];
        ushort* op     = (s == 0) ? qb : (s == 1) ? kb : vb;
        #pragma unroll
        for (int i = 0; i < 8; ++i) {
            #pragma unroll
            for (int r = 0; r < 4; ++r) {
                const int gr = row0 + wm * 128 + i * 16 + kh * 4 + r;
                if (gr < M)
                    op[(size_t)gr * DIMC + cb] = f2bf(acc[i][n][r] + bb);
            }
        }
    }
}

// ---------------------------------------------------------------------------
// Final GEMM (fp32 out): 192x256 tile, 3-phase counted-vmcnt schedule.
// Grid 64 mt x 4 nt = 256 blocks = EXACTLY 1 round at 1 block/CU.
// 8 waves (2M x 4N): per-wave out 96 x 64 (6 row-frags x 4 col-frags).
// Per-wave 7 loads/K-tile, slots (issue order): B(4) Ap0(1) Ap1(1) Ap2(1).
//   p0 wait vmcnt(2): retires B,Ap0 -> read ALL B-frags + A rf0,1; issue 5
//   p1 wait vmcnt(6): retires Ap1   -> read A rf2,3;               issue Ap1
//   p2 wait vmcnt(6): retires Ap2   -> read A rf4,5;               issue Ap2
// A-phase-i rows = [i*32,i*32+32) u [96+i*32,96+i*32+32); wave w stages row
// base (w<4 ? w*8 : 96+(w-4)*8) + i*32.  B rows: wave w owns [w*32,w*32+32).
// LDS 112KB dbuf (A 192x64 at 0, B 256x64 at 192*64); same XOR swizzle.
// ---------------------------------------------------------------------------
__global__ __launch_bounds__(512, 2) void gemmF(
    const ushort* __restrict__ A, const ushort* __restrict__ Bt,
    const float* __restrict__ bias, float* __restrict__ C, int M)
{
    __shared__ ushort lds[2][(192 + 256) * 64];   // A at 0, B at 192*64 ushorts

    const int bid = blockIdx.x;
    const int xcd = bid & 7;
    const int j   = bid >> 3;                     // 0..31
    const int mt  = xcd * 8 + (j % 8);            // 0..63
    const int nt  = j / 8;                        // 0..3
    const int row0 = mt * 192;
    const int col0 = nt * 256;

    const int t512 = threadIdx.x;
    const int w    = t512 >> 6;
    const int lane = t512 & 63;
    const int wm   = w >> 2;                      // 0..1
    const int wn   = w & 3;                       // 0..3
    const int l15  = lane & 15;
    const int kh   = lane >> 4;                   // 0..3

    const int awbase = (w & 4) ? (96 + (w - 4) * 8) : (w * 8);  // A-staging row base

    auto stage = [&](int buf, int kt, int mat, int relRow) {
        const int o   = relRow * 128 + lane * 16;
        const int row = o >> 7;
        const int kb_ = (o & 127) ^ ((row & 7) << 4);
        const ushort* src = (mat ? Bt + (size_t)(col0 + row) * DIMC
                                 : A  + (size_t)(row0 + row) * DIMC)
                            + kt * 64 + (kb_ >> 1);
        gload_lds16(src, &lds[buf][0] + mat * (192 * 64) + relRow * 64);
    };
    auto rdA = [&](int buf, int fr, int ks) -> bf16x8 {
        const int row = wm * 96 + fr * 16 + l15;
        const int ad  = (row * 128 + ks * 64 + kh * 16) ^ ((row & 7) << 4);
        return *(const bf16x8*)(&lds[buf][0] + (ad >> 1));
    };
    auto rdB = [&](int buf, int n, int ks) -> bf16x8 {
        const int row = wn * 64 + n * 16 + l15;
        const int ad  = (row * 128 + ks * 64 + kh * 16) ^ ((row & 7) << 4);
        return *(const bf16x8*)(&lds[buf][192 * 64] + (ad >> 1));
    };

    f32x4 acc[6][4] = {};
    bf16x8 af[2][2];        // current 2 row-frags
    bf16x8 bf[4][2];        // all 4 col-frags, read once per K-tile

    // prologue: tile 0 -> buf 0, slot order B(4) Ap0 Ap1 Ap2
    stage(0, 0, 1, w * 32);
    stage(0, 0, 1, w * 32 + 8);
    stage(0, 0, 1, w * 32 + 16);
    stage(0, 0, 1, w * 32 + 24);
    stage(0, 0, 0, awbase);
    stage(0, 0, 0, awbase + 32);
    stage(0, 0, 0, awbase + 64);

    const int NT = DIMC / 64;    // 16
    for (int t = 0; t < NT; ++t) {
        const int cur = t & 1;
        const int nxt = cur ^ 1;
        const int tn  = (t + 1 < NT) ? (t + 1) : (NT - 1);

        // -------- phase 0: rf0,1 x all 64 cols --------
        asm volatile("s_waitcnt vmcnt(2)" ::: "memory");
        __builtin_amdgcn_s_barrier();
        __builtin_amdgcn_sched_barrier(0);
        #pragma unroll
        for (int fr = 0; fr < 2; ++fr)
            #pragma unroll
            for (int ks = 0; ks < 2; ++ks)
                af[fr][ks] = rdA(cur, fr, ks);
        #pragma unroll
        for (int n = 0; n < 4; ++n)
            #pragma unroll
            for (int ks = 0; ks < 2; ++ks)
                bf[n][ks] = rdB(cur, n, ks);
        stage(nxt, tn, 1, w * 32);
        stage(nxt, tn, 1, w * 32 + 8);
        stage(nxt, tn, 1, w * 32 + 16);
        stage(nxt, tn, 1, w * 32 + 24);
        stage(nxt, tn, 0, awbase);
        __builtin_amdgcn_s_setprio(1);
        #pragma unroll
        for (int fr = 0; fr < 2; ++fr)
            #pragma unroll
            for (int n = 0; n < 4; ++n)
                #pragma unroll
                for (int ks = 0; ks < 2; ++ks)
                    acc[fr][n] = __builtin_amdgcn_mfma_f32_16x16x32_bf16(
                        af[fr][ks], bf[n][ks], acc[fr][n], 0, 0, 0);
        __builtin_amdgcn_s_setprio(0);

        // -------- phase 1: rf2,3 --------
        asm volatile("s_waitcnt vmcnt(6)" ::: "memory");
        __builtin_amdgcn_s_barrier();
        __builtin_amdgcn_sched_barrier(0);
        #pragma unroll
        for (int fr = 0; fr < 2; ++fr)
            #pragma unroll
            for (int ks = 0; ks < 2; ++ks)
                af[fr][ks] = rdA(cur, 2 + fr, ks);
        stage(nxt, tn, 0, awbase + 32);
        __builtin_amdgcn_s_setprio(1);
        #pragma unroll
        for (int fr = 0; fr < 2; ++fr)
            #pragma unroll
            for (int n = 0; n < 4; ++n)
                #pragma unroll
                for (int ks = 0; ks < 2; ++ks)
                    acc[2 + fr][n] = __builtin_amdgcn_mfma_f32_16x16x32_bf16(
                        af[fr][ks], bf[n][ks], acc[2 + fr][n], 0, 0, 0);
        __builtin_amdgcn_s_setprio(0);

        // -------- phase 2: rf4,5 --------
        asm volatile("s_waitcnt vmcnt(6)" ::: "memory");
        __builtin_amdgcn_s_barrier();
        __builtin_amdgcn_sched_barrier(0);
        #pragma unroll
        for (int fr = 0; fr < 2; ++fr)
            #pragma unroll
            for (int ks = 0; ks < 2; ++ks)
                af[fr][ks] = rdA(cur, 4 + fr, ks);
        stage(nxt, tn, 0, awbase + 64);
        __builtin_amdgcn_s_setprio(1);
        #pragma unroll
        for (int fr = 0; fr < 2; ++fr)
            #pragma unroll
            for (int n = 0; n < 4; ++n)
                #pragma unroll
                for (int ks = 0; ks < 2; ++ks)
                    acc[4 + fr][n] = __builtin_amdgcn_mfma_f32_16x16x32_bf16(
                        af[fr][ks], bf[n][ks], acc[4 + fr][n], 0, 0, 0);
        __builtin_amdgcn_s_setprio(0);
    }

    // epilogue
    #pragma unroll
    for (int n = 0; n < 4; ++n) {
        const int c  = col0 + wn * 64 + n * 16 + l15;
        const float bb = bias[c];
        #pragma unroll
        for (int i = 0; i < 6; ++i) {
            #pragma unroll
            for (int r = 0; r < 4; ++r) {
                const int gr = row0 + wm * 96 + i * 16 + kh * 4 + r;
                if (gr < M)
                    C[(size_t)gr * DIMC + c] = acc[i][n][r] + bb;
            }
        }
    }
}

// ---------------------------------------------------------------------------
__global__ __launch_bounds__(256) void cvt_pad(
    const float* __restrict__ x, ushort* __restrict__ xb, int nvalid, int ntot)
{
    const int stride = gridDim.x * blockDim.x;
    for (int i = blockIdx.x * blockDim.x + threadIdx.x; i < ntot / 4; i += stride) {
        const int e = i * 4;
        ushort4 o;
        if (e < nvalid) {
            const float4 f = *(const float4*)(x + e);
            o.x = f2bf(f.x); o.y = f2bf(f.y); o.z = f2bf(f.z); o.w = f2bf(f.w);
        } else { o.x = o.y = o.z = o.w = 0; }
        *(ushort4*)(xb + e) = o;
    }
}

__global__ __launch_bounds__(256) void transpose_w4(
    const float* __restrict__ W0, const float* __restrict__ W1,
    const float* __restrict__ W2, const float* __restrict__ W3,
    ushort* __restrict__ T0, ushort* __restrict__ T1,
    ushort* __restrict__ T2, ushort* __restrict__ T3)
{
    __shared__ float tile[32][33];
    const int z = blockIdx.z;
    const float* W = (z == 0) ? W0 : (z == 1) ? W1 : (z == 2) ? W2 : W3;
    ushort*      T = (z == 0) ? T0 : (z == 1) ? T1 : (z == 2) ? T2 : T3;
    const int tx = threadIdx.x & 31;
    const int ty = threadIdx.x >> 5;
    const int n0 = blockIdx.x * 32;
    const int k0 = blockIdx.y * 32;
    #pragma unroll
    for (int i = 0; i < 32; i += 8)
        tile[ty + i][tx] = W[(size_t)(k0 + ty + i) * DIMC + n0 + tx];
    __syncthreads();
    #pragma unroll
    for (int i = 0; i < 32; i += 8)
        T[(size_t)(n0 + ty + i) * DIMC + k0 + tx] = f2bf(tile[tx][ty + i]);
}

// ---------------------------------------------------------------------------
// MFMA flash attention (unchanged from round 6 — verified passing).
// ---------------------------------------------------------------------------
__global__ __launch_bounds__(64) void attn_mfma(
    const ushort* __restrict__ qg, const ushort* __restrict__ kg,
    const ushort* __restrict__ vg, ushort* __restrict__ og,
    const int* __restrict__ lens, int B)
{
    __shared__ ushort Vt[64 * 68];

    const int i   = blockIdx.x;
    const int xcd = i & 7;
    const int j   = i >> 3;
    const int bh  = xcd * (B * 2) + (j >> 2);
    const int qt  = j & 3;
    const int h   = bh & 15;
    const int b   = bh >> 4;

    const int lane = threadIdx.x & 63;

    const int myl = (lane < B) ? lens[lane] : 0;
    int inc = myl;
    #pragma unroll
    for (int d = 1; d < 64; d <<= 1) {
        const int nb = __shfl_up(inc, d);
        if (lane >= d) inc += nb;
    }
    const int off = __shfl(inc, b) - __shfl(myl, b);
    const int L   = __shfl(myl, b);
    if (qt * 64 >= L) return;
    const int ntk = (L + 63) >> 6;

    const int l31 = lane & 31;
    const int hi  = lane >> 5;
    const int kp  = lane & 31;
    const int dh  = lane >> 5;

    bf16x8 qf[2][4];
    #pragma unroll
    for (int qn = 0; qn < 2; ++qn) {
        const size_t row = (size_t)(off + min(qt * 64 + qn * 32 + l31, L - 1));
        #pragma unroll
        for (int ks = 0; ks < 4; ++ks) {
            union { uint4 u4; ushort us[8]; bf16x8 v; } tmp;
            tmp.u4 = *(const uint4*)(qg + row * DIMC + h * HDIM + ks * 16 + hi * 8);
            #pragma unroll
            for (int e = 0; e < 8; ++e)
                tmp.us[e] = f2bf(bf2f(tmp.us[e]) * 0.03125f);
            qf[qn][ks] = tmp.v;
        }
    }

    f32x16 o[2][2] = {};
    float mst[2] = {-1e30f, -1e30f};
    float lst[2] = {0.f, 0.f};

    uint4 va[4], vbr[4];
    auto issueV = [&](int tt) {
        const int j0s = tt * 64;
        #pragma unroll
        for (int it = 0; it < 4; ++it) {
            const int d0 = (it * 2 + dh) * 8;
            const size_t r0 = (size_t)(off + min(j0s + 2 * kp,     L - 1));
            const size_t r1 = (size_t)(off + min(j0s + 2 * kp + 1, L - 1));
            va[it]  = *(const uint4*)(vg + r0 * DIMC + h * HDIM + d0);
            vbr[it] = *(const uint4*)(vg + r1 * DIMC + h * HDIM + d0);
        }
    };

    bf16x8 kfc[2][4], kfn[2][4];
    auto loadK = [&](int tt, bf16x8 (&kf)[2][4]) {
        const int j0s = tt * 64;
        #pragma unroll
        for (int km = 0; km < 2; ++km) {
            const size_t row = (size_t)(off + min(j0s + km * 32 + l31, L - 1));
            #pragma unroll
            for (int ks = 0; ks < 4; ++ks)
                kf[km][ks] = *(const bf16x8*)(kg + row * DIMC + h * HDIM + ks * 16 + hi * 8);
        }
    };

    issueV(0);
    loadK(0, kfc);

    for (int t = 0; t < ntk; ++t) {
        const int j0 = t * 64;

        loadK(min(t + 1, ntk - 1), kfn);

        f32x16 s[2][2] = {};
        __builtin_amdgcn_s_setprio(1);
        #pragma unroll
        for (int km = 0; km < 2; ++km)
            #pragma unroll
            for (int qn = 0; qn < 2; ++qn)
                #pragma unroll
                for (int ks = 0; ks < 4; ++ks)
                    s[km][qn] = __builtin_amdgcn_mfma_f32_32x32x16_bf16(
                        kfc[km][ks], qf[qn][ks], s[km][qn], 0, 0, 0);
        __builtin_amdgcn_s_setprio(0);

        #pragma unroll
        for (int it = 0; it < 4; ++it) {
            const int d0 = (it * 2 + dh) * 8;
            const uint a4[4] = {va[it].x,  va[it].y,  va[it].z,  va[it].w};
            const uint b4[4] = {vbr[it].x, vbr[it].y, vbr[it].z, vbr[it].w};
            #pragma unroll
            for (int jj = 0; jj < 4; ++jj) {
                const uint lo  = (a4[jj] & 0xffffu) | (b4[jj] << 16);
                const uint hi2 = (a4[jj] >> 16) | (b4[jj] & 0xffff0000u);
                *(uint*)&Vt[(d0 + 2 * jj)     * 68 + 2 * kp] = lo;
                *(uint*)&Vt[(d0 + 2 * jj + 1) * 68 + 2 * kp] = hi2;
            }
        }
        if (t + 1 < ntk) issueV(t + 1);

        const bool fullTile = (j0 + 64 <= L);
        float tmv[2];
        #pragma unroll
        for (int qn = 0; qn < 2; ++qn) {
            float tm = -1e30f;
            if (fullTile) {
                #pragma unroll
                for (int km = 0; km < 2; ++km)
                    #pragma unroll
                    for (int r = 0; r < 16; ++r)
                        tm = fmaxf(tm, s[km][qn][r]);
            } else {
                #pragma unroll
                for (int km = 0; km < 2; ++km)
                    #pragma unroll
                    for (int r = 0; r < 16; ++r) {
                        const int key = j0 + km * 32 + (r & 3) + 8 * (r >> 2) + 4 * hi;
                        float sv = s[km][qn][r];
                        sv = (key < L) ? sv : -1e30f;
                        s[km][qn][r] = sv;
                        tm = fmaxf(tm, sv);
                    }
            }
            tm = fmaxf(tm, __shfl_xor(tm, 32));
            tmv[qn] = tm;
        }

        const bool need = (tmv[0] > mst[0] + 4.f) || (tmv[1] > mst[1] + 4.f);
        if (__any(need)) {
            #pragma unroll
            for (int qn = 0; qn < 2; ++qn) {
                const float nm = fmaxf(mst[qn], tmv[qn]);
                const float corr = __expf(mst[qn] - nm);
                mst[qn] = nm;
                lst[qn] *= corr;
                #pragma unroll
                for (int dm = 0; dm < 2; ++dm)
                    #pragma unroll
                    for (int r = 0; r < 16; ++r)
                        o[dm][qn][r] *= corr;
            }
        }
        #pragma unroll
        for (int qn = 0; qn < 2; ++qn) {
            float ls = 0.f;
            #pragma unroll
            for (int km = 0; km < 2; ++km)
                #pragma unroll
                for (int r = 0; r < 16; ++r) {
                    const float p = __expf(s[km][qn][r] - mst[qn]);
                    s[km][qn][r] = p;
                    ls += p;
                }
            ls += __shfl_xor(ls, 32);
            lst[qn] += ls;
        }

        #pragma unroll
        for (int kspv = 0; kspv < 4; ++kspv) {
            const int km = kspv >> 1;
            const int sb = kspv & 1;

            bf16x8 Afr[2];
            #pragma unroll
            for (int dm = 0; dm < 2; ++dm) {
                const int d = dm * 32 + l31;
                const uint2 p0 = *(const uint2*)&Vt[d * 68 + kspv * 16 + hi * 8];
                const uint2 p1 = *(const uint2*)&Vt[d * 68 + kspv * 16 + hi * 8 + 4];
                union { uint u[4]; bf16x8 v; } aa;
                aa.u[0] = p0.x; aa.u[1] = p0.y; aa.u[2] = p1.x; aa.u[3] = p1.y;
                Afr[dm] = aa.v;
            }

            bf16x8 Bfr[2];
            #pragma unroll
            for (int qn = 0; qn < 2; ++qn) {
                const uint X0 = pkbf(s[km][qn][8 * sb + 0], s[km][qn][8 * sb + 1]);
                const uint X1 = pkbf(s[km][qn][8 * sb + 2], s[km][qn][8 * sb + 3]);
                const uint Y0 = pkbf(s[km][qn][8 * sb + 4], s[km][qn][8 * sb + 5]);
                const uint Y1 = pkbf(s[km][qn][8 * sb + 6], s[km][qn][8 * sb + 7]);
                const uint sx0 = (uint)__shfl_xor((int)X0, 32);
                const uint sx1 = (uint)__shfl_xor((int)X1, 32);
                const uint sy0 = (uint)__shfl_xor((int)Y0, 32);
                const uint sy1 = (uint)__shfl_xor((int)Y1, 32);
                union { uint u[4]; bf16x8 v; } bb;
                bb.u[0] = hi ? sy0 : X0;
                bb.u[1] = hi ? sy1 : X1;
                bb.u[2] = hi ? Y0 : sx0;
                bb.u[3] = hi ? Y1 : sx1;
                Bfr[qn] = bb.v;
            }

            __builtin_amdgcn_s_setprio(1);
            #pragma unroll
            for (int dm = 0; dm < 2; ++dm)
                #pragma unroll
                for (int qn = 0; qn < 2; ++qn)
                    o[dm][qn] = __builtin_amdgcn_mfma_f32_32x32x16_bf16(
                        Afr[dm], Bfr[qn], o[dm][qn], 0, 0, 0);
            __builtin_amdgcn_s_setprio(0);
        }

        #pragma unroll
        for (int km = 0; km < 2; ++km)
            #pragma unroll
            for (int ks = 0; ks < 4; ++ks)
                kfc[km][ks] = kfn[km][ks];
    }

    #pragma unroll
    for (int qn = 0; qn < 2; ++qn) {
        const int q = qt * 64 + qn * 32 + l31;
        if (q < L) {
            const float inv = 1.f / lst[qn];
            ushort* orow = og + (size_t)(off + q) * DIMC + h * HDIM;
            #pragma unroll
            for (int dm = 0; dm < 2; ++dm)
                #pragma unroll
                for (int bq2 = 0; bq2 < 4; ++bq2) {
                    const int r0 = 4 * bq2;
                    uint2 st;
                    st.x = pkbf(o[dm][qn][r0 + 0] * inv, o[dm][qn][r0 + 1] * inv);
                    st.y = pkbf(o[dm][qn][r0 + 2] * inv, o[dm][qn][r0 + 3] * inv);
                    *(uint2*)(orow + dm * 32 + 8 * bq2 + 4 * hi) = st;
                }
        }
    }
}

// ---------------------------------------------------------------------------
extern "C" void kernel_launch(void* const* d_in, const int* in_sizes, int n_in,
                              void* d_out, int out_size, void* d_ws, size_t ws_size,
                              hipStream_t stream)
{
    const float* x   = (const float*)d_in[0];
    const float* Wq  = (const float*)d_in[1];
    const float* bq  = (const float*)d_in[2];
    const float* Wk  = (const float*)d_in[3];
    const float* bk  = (const float*)d_in[4];
    const float* Wv  = (const float*)d_in[5];
    const float* bv  = (const float*)d_in[6];
    const float* Wu  = (const float*)d_in[7];
    const float* bu  = (const float*)d_in[8];
    const int*  lens = (const int*)d_in[9];

    const int N = in_sizes[0] / DIMC;    // 12224
    const int B = in_sizes[9];           // 64

    ushort* xb  = (ushort*)d_ws;                         // MPAD*1024 bf16
    ushort* wtq = xb  + (size_t)MPAD * DIMC;             // 3 contiguous = Wt_cat
    ushort* wtk = wtq + (size_t)DIMC * DIMC;
    ushort* wtv = wtk + (size_t)DIMC * DIMC;
    ushort* wtu = wtv + (size_t)DIMC * DIMC;
    ushort* kb  = wtu + (size_t)DIMC * DIMC;             // N*1024 bf16
    ushort* vb  = kb  + (size_t)N * DIMC;                // N*1024 bf16
    ushort* qb  = (ushort*)d_out;                        // q lives in d_out (bf16)
    ushort* ob  = xb;                                    // attn out reuses xb

    cvt_pad<<<2048, 256, 0, stream>>>(x, xb, N * DIMC, MPAD * DIMC);
    transpose_w4<<<dim3(32, 32, 4), 256, 0, stream>>>(Wq, Wk, Wv, Wu,
                                                      wtq, wtk, wtv, wtu);

    // fused QKV: 48 mt x 16 nt = 768 blocks = 3 exact rounds
    gemm192<<<768, 512, 0, stream>>>(xb, wtq, bq, bk, bv, qb, kb, vb, N);

    attn_mfma<<<dim3(B * NHEAD * 4), dim3(64), 0, stream>>>(qb, kb, vb, ob, lens, B);

    // final: 64 mt x 4 nt = 256 blocks = 1 exact round
    gemmF<<<256, 512, 0, stream>>>(ob, wtu, bu, (float*)d_out, N);
}